// Round 1
// baseline (868.126 us; speedup 1.0000x reference)
//
#include <hip/hip_runtime.h>

// ---------------------------------------------------------------------------
// GCN 2-layer forward: out = A_hat @ relu(A_hat @ (x@W1) + b1) @ W2 + b2
// A_hat = D^-1/2 (A + I) D^-1/2, atomics-based scatter-add aggregation.
// ---------------------------------------------------------------------------

__global__ void k_init_deg(float* __restrict__ deg, int n) {
    int i = blockIdx.x * blockDim.x + threadIdx.x;
    if (i < n) deg[i] = 1.0f;   // self-loop contributes 1 to every node
}

__global__ void k_deg(const int* __restrict__ dst, int E, float* __restrict__ deg) {
    int i = blockIdx.x * blockDim.x + threadIdx.x;
    if (i < E) atomicAdd(&deg[dst[i]], 1.0f);
}

__global__ void k_rsqrt(float* __restrict__ deg, int n) {
    int i = blockIdx.x * blockDim.x + threadIdx.x;
    if (i < n) deg[i] = rsqrtf(deg[i]);   // deg >= 1 always (self-loops)
}

// h[n,64] = x[n,128] @ W[128,64].  Block: 256 threads = 4 rows x 64 cols.
__global__ __launch_bounds__(256) void k_gemm1(const float* __restrict__ x,
                                               const float* __restrict__ W,
                                               float* __restrict__ h, int n) {
    __shared__ float Ws[128 * 64];   // 32 KB
    __shared__ float xs[4 * 128];    // 2 KB
    for (int i = threadIdx.x; i < 128 * 64; i += 256) Ws[i] = W[i];
    int row0 = blockIdx.x * 4;
    for (int i = threadIdx.x; i < 4 * 128; i += 256) {
        int r = i >> 7, k = i & 127;
        int row = row0 + r;
        xs[i] = (row < n) ? x[row * 128 + k] : 0.0f;
    }
    __syncthreads();
    int r = threadIdx.x >> 6;   // 0..3
    int c = threadIdx.x & 63;   // 0..63
    float sum = 0.0f;
#pragma unroll 16
    for (int k = 0; k < 128; ++k)
        sum += xs[r * 128 + k] * Ws[k * 64 + c];   // xs broadcast, Ws conflict-free
    int row = row0 + r;
    if (row < n) h[row * 64 + c] = sum;
}

// agg1[i,f] = hlin[i,f]*dinv[i]^2 + b1[f]   (self-loop + bias folded in)
__global__ void k_init_agg1(const float* __restrict__ h, const float* __restrict__ dinv,
                            const float* __restrict__ b1, float* __restrict__ agg, int n) {
    int idx = blockIdx.x * blockDim.x + threadIdx.x;
    if (idx < n * 64) {
        int i = idx >> 6, f = idx & 63;
        float d = dinv[i];
        agg[idx] = h[idx] * d * d + b1[f];
    }
}

// One 64-lane wave per edge, lane = feature. 4 edges per 256-thread block.
__global__ __launch_bounds__(256) void k_scatter1(const float* __restrict__ h,
                                                  const int* __restrict__ src,
                                                  const int* __restrict__ dst,
                                                  const float* __restrict__ dinv,
                                                  float* __restrict__ agg, int E) {
    int e = blockIdx.x * 4 + (threadIdx.x >> 6);
    if (e >= E) return;
    int f = threadIdx.x & 63;
    int s = src[e], d = dst[e];
    float w = dinv[s] * dinv[d];
    atomicAdd(&agg[d * 64 + f], h[s * 64 + f] * w);
}

// h2[n,40] = relu(agg1)[n,64] @ W2[64,40].  Block (40,8) = 320 threads, 8 rows.
__global__ __launch_bounds__(320) void k_gemm2(const float* __restrict__ agg,
                                               const float* __restrict__ W2,
                                               float* __restrict__ h2, int n) {
    __shared__ float Ws[64 * 40];   // 10 KB
    __shared__ float hs[8 * 64];    // 2 KB
    int tid = threadIdx.y * 40 + threadIdx.x;
    for (int i = tid; i < 64 * 40; i += 320) Ws[i] = W2[i];
    int row0 = blockIdx.x * 8;
    for (int i = tid; i < 8 * 64; i += 320) {
        int r = i >> 6, k = i & 63;
        int row = row0 + r;
        float v = (row < n) ? agg[row * 64 + k] : 0.0f;
        hs[i] = v > 0.0f ? v : 0.0f;   // fused ReLU
    }
    __syncthreads();
    int c = threadIdx.x, r = threadIdx.y;
    float sum = 0.0f;
#pragma unroll
    for (int k = 0; k < 64; ++k)
        sum += hs[r * 64 + k] * Ws[k * 40 + c];
    int row = row0 + r;
    if (row < n) h2[row * 40 + c] = sum;
}

// out[i,f] = h2[i,f]*dinv[i]^2 + b2[f]
__global__ void k_init_out(const float* __restrict__ h2, const float* __restrict__ dinv,
                           const float* __restrict__ b2, float* __restrict__ out, int n) {
    int idx = blockIdx.x * blockDim.x + threadIdx.x;
    if (idx < n * 40) {
        int i = idx / 40;
        int f = idx - i * 40;
        float d = dinv[i];
        out[idx] = h2[idx] * d * d + b2[f];
    }
}

// One thread per (edge, feature); e = idx/40 (const-div -> magic multiply).
__global__ __launch_bounds__(256) void k_scatter2(const float* __restrict__ h2,
                                                  const int* __restrict__ src,
                                                  const int* __restrict__ dst,
                                                  const float* __restrict__ dinv,
                                                  float* __restrict__ out, int E) {
    int idx = blockIdx.x * blockDim.x + threadIdx.x;
    int total = E * 40;
    if (idx >= total) return;
    int e = idx / 40;
    int f = idx - e * 40;
    int s = src[e], d = dst[e];
    float w = dinv[s] * dinv[d];
    atomicAdd(&out[d * 40 + f], h2[s * 40 + f] * w);
}

extern "C" void kernel_launch(void* const* d_in, const int* in_sizes, int n_in,
                              void* d_out, int out_size, void* d_ws, size_t ws_size,
                              hipStream_t stream) {
    const float* x  = (const float*)d_in[0];
    const int*   ei = (const int*)d_in[1];
    const float* W1 = (const float*)d_in[2];
    const float* b1 = (const float*)d_in[3];
    const float* W2 = (const float*)d_in[4];
    const float* b2 = (const float*)d_in[5];
    float* out = (float*)d_out;

    const int n = in_sizes[0] / 128;   // 100000
    const int E = in_sizes[1] / 2;     // 1600000
    const int* src = ei;
    const int* dst = ei + E;

    char* ws = (char*)d_ws;
    float* dinv = (float*)(ws);                       // 0.4 MB
    float* hlin = (float*)(ws + (size_t)(1 << 20));   // 25.6 MB  (reused as h2)
    float* agg1 = (float*)(ws + (size_t)27 * (1 << 20)); // 25.6 MB
    float* h2 = hlin;

    // 1. degree (init to 1 for self-loops) + atomic accumulate + rsqrt
    k_init_deg<<<(n + 255) / 256, 256, 0, stream>>>(dinv, n);
    k_deg<<<(E + 255) / 256, 256, 0, stream>>>(dst, E, dinv);
    k_rsqrt<<<(n + 255) / 256, 256, 0, stream>>>(dinv, n);

    // 2. hlin = x @ W1
    k_gemm1<<<(n + 3) / 4, 256, 0, stream>>>(x, W1, hlin, n);

    // 3. agg1 = self-loop + bias, then scatter edges
    k_init_agg1<<<(n * 64 + 255) / 256, 256, 0, stream>>>(hlin, dinv, b1, agg1, n);
    k_scatter1<<<(E + 3) / 4, 256, 0, stream>>>(hlin, src, dst, dinv, agg1, E);

    // 4. h2 = relu(agg1) @ W2
    dim3 blk2(40, 8);
    k_gemm2<<<(n + 7) / 8, blk2, 0, stream>>>(agg1, W2, h2, n);

    // 5. out = self-loop + bias, then scatter edges
    k_init_out<<<(n * 40 + 255) / 256, 256, 0, stream>>>(h2, dinv, b2, out, n);
    int total2 = E * 40;
    k_scatter2<<<(total2 + 255) / 256, 256, 0, stream>>>(h2, src, dst, dinv, out, E);
}

// Round 2
// 499.374 us; speedup vs baseline: 1.7384x; 1.7384x over previous
//
#include <hip/hip_runtime.h>

// ---------------------------------------------------------------------------
// GCN 2-layer forward: out = A_hat @ relu(A_hat @ (x@W1) + b1) @ W2 + b2
// A_hat = D^-1/2 (A + I) D^-1/2.
// Strategy: build CSC (in-edges by dst) on device, then gather-aggregate
// (1 wave per dst node, no output atomics). Self-loop + bias folded into
// the gather. Fallback to atomic-scatter path if ws_size is too small.
// ---------------------------------------------------------------------------

__global__ void k_init_deg(float* __restrict__ deg, int n) {
    int i = blockIdx.x * blockDim.x + threadIdx.x;
    if (i < n) deg[i] = 1.0f;   // self-loop contributes 1 to every node
}

__global__ void k_deg(const int* __restrict__ dst, int E, float* __restrict__ deg) {
    int i = blockIdx.x * blockDim.x + threadIdx.x;
    if (i < E) atomicAdd(&deg[dst[i]], 1.0f);
}

__global__ void k_rsqrt(float* __restrict__ deg, int n) {
    int i = blockIdx.x * blockDim.x + threadIdx.x;
    if (i < n) deg[i] = rsqrtf(deg[i]);   // deg >= 1 always (self-loops)
}

// ---- CSC build: exclusive scan of in-degree counts (2-level) --------------

// Per-block inclusive scan (Hillis-Steele in LDS); writes exclusive result.
__global__ __launch_bounds__(256) void k_scan_block(const float* __restrict__ degf,
                                                    int* __restrict__ off,
                                                    int* __restrict__ partial, int n) {
    __shared__ int tmp[256];
    int i = blockIdx.x * 256 + threadIdx.x;
    int v = (i < n) ? ((int)(degf[i] + 0.5f) - 1) : 0;   // edge count (minus self-loop)
    tmp[threadIdx.x] = v;
    __syncthreads();
    for (int ofs = 1; ofs < 256; ofs <<= 1) {
        int t = (threadIdx.x >= ofs) ? tmp[threadIdx.x - ofs] : 0;
        __syncthreads();
        if (threadIdx.x >= ofs) tmp[threadIdx.x] += t;
        __syncthreads();
    }
    if (i < n) off[i] = tmp[threadIdx.x] - v;   // exclusive
    if (threadIdx.x == 255) partial[blockIdx.x] = tmp[255];
}

// Single-block exclusive scan of block totals (nb <= 512).
__global__ __launch_bounds__(512) void k_scan_partial(int* __restrict__ partial, int nb) {
    __shared__ int tmp[512];
    int v = (threadIdx.x < nb) ? partial[threadIdx.x] : 0;
    tmp[threadIdx.x] = v;
    __syncthreads();
    for (int ofs = 1; ofs < 512; ofs <<= 1) {
        int t = (threadIdx.x >= ofs) ? tmp[threadIdx.x - ofs] : 0;
        __syncthreads();
        if (threadIdx.x >= ofs) tmp[threadIdx.x] += t;
        __syncthreads();
    }
    if (threadIdx.x < nb) partial[threadIdx.x] = tmp[threadIdx.x] - v;
}

__global__ void k_scan_add(int* __restrict__ off, const int* __restrict__ partial,
                           int* __restrict__ cursor, int n) {
    int i = blockIdx.x * blockDim.x + threadIdx.x;
    if (i < n) {
        int o = off[i] + partial[i >> 8];
        off[i] = o;
        cursor[i] = o;
    }
}

__global__ void k_fill(const int* __restrict__ src, const int* __restrict__ dst,
                       int* __restrict__ cursor, int* __restrict__ csrc, int E) {
    int i = blockIdx.x * blockDim.x + threadIdx.x;
    if (i < E) {
        int p = atomicAdd(&cursor[dst[i]], 1);
        csrc[p] = src[i];
    }
}

// ---- dense layers ----------------------------------------------------------

// h[n,64] = x[n,128] @ W[128,64]. 256 thr, 16 rows/block, 4 outputs/thread.
__global__ __launch_bounds__(256) void k_gemm1(const float* __restrict__ x,
                                               const float* __restrict__ W,
                                               float* __restrict__ h, int n) {
    __shared__ float Ws[128 * 64];   // 32 KB
    __shared__ float xs[16 * 128];   // 8 KB
    for (int i = threadIdx.x; i < 128 * 64; i += 256) Ws[i] = W[i];
    int row0 = blockIdx.x * 16;
    for (int i = threadIdx.x; i < 16 * 128; i += 256) {
        int r = i >> 7, k = i & 127;
        int row = row0 + r;
        xs[i] = (row < n) ? x[row * 128 + k] : 0.0f;
    }
    __syncthreads();
    int c = threadIdx.x & 63;        // feature col
    int r0 = threadIdx.x >> 6;       // 0..3 -> rows r0, r0+4, r0+8, r0+12
    float s0 = 0.f, s1 = 0.f, s2 = 0.f, s3 = 0.f;
#pragma unroll 8
    for (int k = 0; k < 128; ++k) {
        float w = Ws[k * 64 + c];
        s0 += xs[(r0     ) * 128 + k] * w;
        s1 += xs[(r0 +  4) * 128 + k] * w;
        s2 += xs[(r0 +  8) * 128 + k] * w;
        s3 += xs[(r0 + 12) * 128 + k] * w;
    }
    if (row0 + r0      < n) h[(row0 + r0     ) * 64 + c] = s0;
    if (row0 + r0 +  4 < n) h[(row0 + r0 +  4) * 64 + c] = s1;
    if (row0 + r0 +  8 < n) h[(row0 + r0 +  8) * 64 + c] = s2;
    if (row0 + r0 + 12 < n) h[(row0 + r0 + 12) * 64 + c] = s3;
}

// h2[n,40] = relu(agg1)[n,64] @ W2[64,40]. Block (40,8), 16 rows, 2 out/thread.
__global__ __launch_bounds__(320) void k_gemm2(const float* __restrict__ agg,
                                               const float* __restrict__ W2,
                                               float* __restrict__ h2, int n) {
    __shared__ float Ws[64 * 40];   // 10 KB
    __shared__ float hs[16 * 64];   // 4 KB
    int tid = threadIdx.y * 40 + threadIdx.x;
    for (int i = tid; i < 64 * 40; i += 320) Ws[i] = W2[i];
    int row0 = blockIdx.x * 16;
    for (int i = tid; i < 16 * 64; i += 320) {
        int r = i >> 6, k = i & 63;
        int row = row0 + r;
        float v = (row < n) ? agg[row * 64 + k] : 0.0f;
        hs[i] = v > 0.0f ? v : 0.0f;   // fused ReLU
    }
    __syncthreads();
    int c = threadIdx.x, r = threadIdx.y;   // rows r, r+8
    float s0 = 0.f, s1 = 0.f;
#pragma unroll
    for (int k = 0; k < 64; ++k) {
        float w = Ws[k * 40 + c];
        s0 += hs[r * 64 + k] * w;
        s1 += hs[(r + 8) * 64 + k] * w;
    }
    if (row0 + r     < n) h2[(row0 + r    ) * 40 + c] = s0;
    if (row0 + r + 8 < n) h2[(row0 + r + 8) * 40 + c] = s1;
}

// ---- gather aggregation (no atomics) --------------------------------------

// agg[d,f] = sum_{s in in(d)} h[s,f]*dinv[s]*dinv[d] + h[d,f]*dinv[d]^2 + b1[f]
// One 64-lane wave per dst node; lane = feature. 4 nodes per 256-thr block.
__global__ __launch_bounds__(256) void k_gather1(const float* __restrict__ h,
                                                 const int* __restrict__ off,
                                                 const int* __restrict__ csrc,
                                                 const float* __restrict__ dinv,
                                                 const float* __restrict__ b1,
                                                 float* __restrict__ agg, int n, int E) {
    int node = blockIdx.x * 4 + (threadIdx.x >> 6);
    if (node >= n) return;
    int f = threadIdx.x & 63;
    int beg = off[node];
    int end = (node + 1 < n) ? off[node + 1] : E;
    float dd = dinv[node];
    float acc0 = h[node * 64 + f] * dd * dd + b1[f];   // self-loop + bias
    float acc1 = 0.f;
    int j = beg;
    for (; j + 3 < end; j += 4) {
        int s0 = csrc[j], s1 = csrc[j + 1], s2 = csrc[j + 2], s3 = csrc[j + 3];
        float w0 = dinv[s0] * dd, w1 = dinv[s1] * dd, w2 = dinv[s2] * dd, w3 = dinv[s3] * dd;
        acc0 += h[s0 * 64 + f] * w0;
        acc1 += h[s1 * 64 + f] * w1;
        acc0 += h[s2 * 64 + f] * w2;
        acc1 += h[s3 * 64 + f] * w3;
    }
    for (; j < end; ++j) {
        int s = csrc[j];
        acc0 += h[s * 64 + f] * (dinv[s] * dd);
    }
    agg[node * 64 + f] = acc0 + acc1;
}

// out[d,f] = sum h2[s,f]*w + h2[d,f]*dinv[d]^2 + b2[f], F=40 (lanes 40..63 idle)
__global__ __launch_bounds__(256) void k_gather2(const float* __restrict__ h2,
                                                 const int* __restrict__ off,
                                                 const int* __restrict__ csrc,
                                                 const float* __restrict__ dinv,
                                                 const float* __restrict__ b2,
                                                 float* __restrict__ out, int n, int E) {
    int node = blockIdx.x * 4 + (threadIdx.x >> 6);
    if (node >= n) return;
    int lane = threadIdx.x & 63;
    int f = lane < 40 ? lane : 39;   // lanes >=40 duplicate, don't write
    int beg = off[node];
    int end = (node + 1 < n) ? off[node + 1] : E;
    float dd = dinv[node];
    float acc0 = h2[node * 40 + f] * dd * dd + b2[f];
    float acc1 = 0.f;
    int j = beg;
    for (; j + 3 < end; j += 4) {
        int s0 = csrc[j], s1 = csrc[j + 1], s2 = csrc[j + 2], s3 = csrc[j + 3];
        float w0 = dinv[s0] * dd, w1 = dinv[s1] * dd, w2 = dinv[s2] * dd, w3 = dinv[s3] * dd;
        acc0 += h2[s0 * 40 + f] * w0;
        acc1 += h2[s1 * 40 + f] * w1;
        acc0 += h2[s2 * 40 + f] * w2;
        acc1 += h2[s3 * 40 + f] * w3;
    }
    for (; j < end; ++j) {
        int s = csrc[j];
        acc0 += h2[s * 40 + f] * (dinv[s] * dd);
    }
    if (lane < 40) out[node * 40 + f] = acc0 + acc1;
}

// ---- fallback atomic-scatter path (used only if ws too small) -------------

__global__ void k_init_agg1(const float* __restrict__ h, const float* __restrict__ dinv,
                            const float* __restrict__ b1, float* __restrict__ agg, int n) {
    int idx = blockIdx.x * blockDim.x + threadIdx.x;
    if (idx < n * 64) {
        int i = idx >> 6, f = idx & 63;
        float d = dinv[i];
        agg[idx] = h[idx] * d * d + b1[f];
    }
}

__global__ __launch_bounds__(256) void k_scatter1(const float* __restrict__ h,
                                                  const int* __restrict__ src,
                                                  const int* __restrict__ dst,
                                                  const float* __restrict__ dinv,
                                                  float* __restrict__ agg, int E) {
    int e = blockIdx.x * 4 + (threadIdx.x >> 6);
    if (e >= E) return;
    int f = threadIdx.x & 63;
    int s = src[e], d = dst[e];
    float w = dinv[s] * dinv[d];
    atomicAdd(&agg[d * 64 + f], h[s * 64 + f] * w);
}

__global__ void k_init_out(const float* __restrict__ h2, const float* __restrict__ dinv,
                           const float* __restrict__ b2, float* __restrict__ out, int n) {
    int idx = blockIdx.x * blockDim.x + threadIdx.x;
    if (idx < n * 40) {
        int i = idx / 40;
        int f = idx - i * 40;
        float d = dinv[i];
        out[idx] = h2[idx] * d * d + b2[f];
    }
}

__global__ __launch_bounds__(256) void k_scatter2(const float* __restrict__ h2,
                                                  const int* __restrict__ src,
                                                  const int* __restrict__ dst,
                                                  const float* __restrict__ dinv,
                                                  float* __restrict__ out, int E) {
    int idx = blockIdx.x * blockDim.x + threadIdx.x;
    int total = E * 40;
    if (idx >= total) return;
    int e = idx / 40;
    int f = idx - e * 40;
    int s = src[e], d = dst[e];
    float w = dinv[s] * dinv[d];
    atomicAdd(&out[d * 40 + f], h2[s * 40 + f] * w);
}

extern "C" void kernel_launch(void* const* d_in, const int* in_sizes, int n_in,
                              void* d_out, int out_size, void* d_ws, size_t ws_size,
                              hipStream_t stream) {
    const float* x  = (const float*)d_in[0];
    const int*   ei = (const int*)d_in[1];
    const float* W1 = (const float*)d_in[2];
    const float* b1 = (const float*)d_in[3];
    const float* W2 = (const float*)d_in[4];
    const float* b2 = (const float*)d_in[5];
    float* out = (float*)d_out;

    const int n = in_sizes[0] / 128;   // 100000
    const int E = in_sizes[1] / 2;     // 1600000
    const int* src = ei;
    const int* dst = ei + E;

    char* ws = (char*)d_ws;
    const size_t MB = 1 << 20;
    // layout
    float* dinv   = (float*)(ws);                       // n floats   (<=512KB)
    int*   off    = (int*)  (ws + 512 * 1024);          // n ints
    int*   cursor = (int*)  (ws + 1024 * 1024);         // n ints
    int*   partial= (int*)  (ws + 1536 * 1024);         // <=512 ints
    float* hlin   = (float*)(ws + 2 * MB);              // n*64 floats (25.6MB)
    float* agg1   = (float*)(ws + 28 * MB);             // n*64 floats (25.6MB)
    int*   csrc   = (int*)  (ws + 54 * MB);             // E ints (6.4MB)
    float* h2 = hlin;                                   // reuse
    size_t needed = 54 * MB + (size_t)E * 4;

    // degree (init 1 for self-loop) + accumulate; rsqrt AFTER scan reads counts
    k_init_deg<<<(n + 255) / 256, 256, 0, stream>>>(dinv, n);
    k_deg<<<(E + 255) / 256, 256, 0, stream>>>(dst, E, dinv);

    if (ws_size >= needed) {
        // ---- CSC build ----
        int nb = (n + 255) / 256;   // 391
        k_scan_block<<<nb, 256, 0, stream>>>(dinv, off, partial, n);
        k_scan_partial<<<1, 512, 0, stream>>>(partial, nb);
        k_scan_add<<<nb, 256, 0, stream>>>(off, partial, cursor, n);
        k_rsqrt<<<(n + 255) / 256, 256, 0, stream>>>(dinv, n);
        k_fill<<<(E + 255) / 256, 256, 0, stream>>>(src, dst, cursor, csrc, E);

        // ---- layer 1 ----
        k_gemm1<<<(n + 15) / 16, 256, 0, stream>>>(x, W1, hlin, n);
        k_gather1<<<(n + 3) / 4, 256, 0, stream>>>(hlin, off, csrc, dinv, b1, agg1, n, E);

        // ---- layer 2 ----
        dim3 blk2(40, 8);
        k_gemm2<<<(n + 15) / 16, blk2, 0, stream>>>(agg1, W2, h2, n);
        k_gather2<<<(n + 3) / 4, 256, 0, stream>>>(h2, off, csrc, dinv, b2, out, n, E);
    } else {
        // ---- fallback: atomic scatter path ----
        k_rsqrt<<<(n + 255) / 256, 256, 0, stream>>>(dinv, n);
        k_gemm1<<<(n + 15) / 16, 256, 0, stream>>>(x, W1, hlin, n);
        k_init_agg1<<<(n * 64 + 255) / 256, 256, 0, stream>>>(hlin, dinv, b1, agg1, n);
        k_scatter1<<<(E + 3) / 4, 256, 0, stream>>>(hlin, src, dst, dinv, agg1, E);
        dim3 blk2(40, 8);
        k_gemm2<<<(n + 15) / 16, blk2, 0, stream>>>(agg1, W2, h2, n);
        k_init_out<<<(n * 40 + 255) / 256, 256, 0, stream>>>(h2, dinv, b2, out, n);
        int total2 = E * 40;
        k_scatter2<<<(total2 + 255) / 256, 256, 0, stream>>>(h2, src, dst, dinv, out, E);
    }
}

// Round 3
// 317.406 us; speedup vs baseline: 2.7351x; 1.5733x over previous
//
#include <hip/hip_runtime.h>

// ---------------------------------------------------------------------------
// GCN 2-layer forward: out = A_hat @ relu(A_hat @ (x@W1) + b1) @ W2 + b2
// A_hat = D^-1/2 (A + I) D^-1/2.
// CSC built via locality-aware counting sort (coarse buckets of 128 nodes),
// gathers vectorized float4 with multi-edge waves. dinv folded into GEMMs.
// ---------------------------------------------------------------------------

#define NPB   128     // nodes per coarse bucket
#define NBCAP 1024    // max buckets supported by fast path

// ---------------- CSC build ----------------

__global__ void k_zero(int* __restrict__ p, int m) {
    int i = blockIdx.x * blockDim.x + threadIdx.x;
    if (i < m) p[i] = 0;
}

__global__ __launch_bounds__(256) void k_hist(const int* __restrict__ dst, int E,
                                              int* __restrict__ bcnt, int nb) {
    __shared__ int h[NBCAP];
    for (int i = threadIdx.x; i < nb; i += 256) h[i] = 0;
    __syncthreads();
    int stride = gridDim.x * 256;
    for (int e = blockIdx.x * 256 + threadIdx.x; e < E; e += stride)
        atomicAdd(&h[dst[e] >> 7], 1);
    __syncthreads();
    for (int i = threadIdx.x; i < nb; i += 256)
        if (h[i]) atomicAdd(&bcnt[i], h[i]);
}

__global__ __launch_bounds__(1024) void k_scan_nb(const int* __restrict__ bcnt,
                                                  int* __restrict__ bbase,
                                                  int* __restrict__ bcur, int nb) {
    __shared__ int tmp[NBCAP];
    int t = threadIdx.x;
    int v = (t < nb) ? bcnt[t] : 0;
    tmp[t] = v;
    __syncthreads();
    for (int ofs = 1; ofs < NBCAP; ofs <<= 1) {
        int u = (t >= ofs) ? tmp[t - ofs] : 0;
        __syncthreads();
        if (t >= ofs) tmp[t] += u;
        __syncthreads();
    }
    if (t < nb) {
        int ex = tmp[t] - v;
        bbase[t] = ex;
        bcur[t] = ex;
        if (t == nb - 1) bbase[nb] = tmp[t];
    }
}

// Each block: 4096 edges stashed in registers; LDS hist; one global atomic
// per (block,bucket) to reserve; LDS-cursor scatter of packed src|ldst.
__global__ __launch_bounds__(256) void k_binpass(const int* __restrict__ src,
                                                 const int* __restrict__ dst,
                                                 int* __restrict__ bcur,
                                                 int* __restrict__ pairs,
                                                 int nb, int E) {
    __shared__ int lh[NBCAP];
    __shared__ int lbase[NBCAP];
    for (int i = threadIdx.x; i < nb; i += 256) lh[i] = 0;
    __syncthreads();
    int base = blockIdx.x * 4096;
    int pk[16], bb[16];
#pragma unroll
    for (int k = 0; k < 16; ++k) {
        int e = base + k * 256 + threadIdx.x;
        if (e < E) {
            int d = dst[e];
            int b = d >> 7;
            bb[k] = b;
            pk[k] = src[e] | ((d & (NPB - 1)) << 17);
            atomicAdd(&lh[b], 1);
        } else bb[k] = -1;
    }
    __syncthreads();
    for (int i = threadIdx.x; i < nb; i += 256) {
        int c = lh[i];
        lbase[i] = c ? atomicAdd(&bcur[i], c) : 0;
        lh[i] = 0;
    }
    __syncthreads();
#pragma unroll
    for (int k = 0; k < 16; ++k) {
        if (bb[k] >= 0) {
            int r = atomicAdd(&lh[bb[k]], 1);
            pairs[lbase[bb[k]] + r] = pk[k];
        }
    }
}

// One block per bucket: LDS degree count + scan -> off/dinv; LDS-cursor fill
// of csrc confined to an ~8KB region (L2-merged writes).
__global__ __launch_bounds__(256) void k_bucket_build(const int* __restrict__ pairs,
                                                      const int* __restrict__ bbase,
                                                      int* __restrict__ off,
                                                      int* __restrict__ csrc,
                                                      float* __restrict__ dinv,
                                                      int n, int nb) {
    __shared__ int deg[NPB], sc[NPB], cur[NPB];
    int t = threadIdx.x;
    int bid = blockIdx.x;
    int node0 = bid * NPB;
    int ebeg = bbase[bid], eend = bbase[bid + 1];
    if (t < NPB) deg[t] = 0;
    __syncthreads();
    for (int e = ebeg + t; e < eend; e += 256)
        atomicAdd(&deg[pairs[e] >> 17], 1);
    __syncthreads();
    if (t < NPB) sc[t] = deg[t];
    __syncthreads();
    for (int ofs = 1; ofs < NPB; ofs <<= 1) {
        int u = (t < NPB && t >= ofs) ? sc[t - ofs] : 0;
        __syncthreads();
        if (t < NPB && t >= ofs) sc[t] += u;
        __syncthreads();
    }
    if (t < NPB) {
        int ex = sc[t] - deg[t];
        cur[t] = ex;
        int node = node0 + t;
        if (node < n) {
            off[node] = ebeg + ex;
            dinv[node] = rsqrtf((float)(deg[t] + 1));
        }
    }
    if (t == 0 && bid == nb - 1) off[n] = eend;
    __syncthreads();
    for (int e = ebeg + t; e < eend; e += 256) {
        int pkv = pairs[e];
        int r = atomicAdd(&cur[pkv >> 17], 1);
        csrc[ebeg + r] = pkv & 0x1FFFF;
    }
}

// ---------------- dense layers (dinv folded into epilogue) ----------------

// h[n,64] = x[n,128] @ W[128,64] (* dinv[row] if dinv). 16 rows/block.
__global__ __launch_bounds__(256) void k_gemm1(const float* __restrict__ x,
                                               const float* __restrict__ W,
                                               float* __restrict__ h, int n,
                                               const float* __restrict__ dinv) {
    __shared__ float Ws[128 * 64];
    __shared__ float xs[16 * 128];
    for (int i = threadIdx.x; i < 128 * 64; i += 256) Ws[i] = W[i];
    int row0 = blockIdx.x * 16;
    for (int i = threadIdx.x; i < 16 * 128; i += 256) {
        int r = i >> 7, k = i & 127;
        int row = row0 + r;
        xs[i] = (row < n) ? x[row * 128 + k] : 0.0f;
    }
    __syncthreads();
    int c = threadIdx.x & 63;
    int r0 = threadIdx.x >> 6;
    float s0 = 0.f, s1 = 0.f, s2 = 0.f, s3 = 0.f;
#pragma unroll 8
    for (int k = 0; k < 128; ++k) {
        float w = Ws[k * 64 + c];
        s0 += xs[(r0     ) * 128 + k] * w;
        s1 += xs[(r0 +  4) * 128 + k] * w;
        s2 += xs[(r0 +  8) * 128 + k] * w;
        s3 += xs[(r0 + 12) * 128 + k] * w;
    }
    int ra = row0 + r0, rb = ra + 4, rc2 = ra + 8, rd = ra + 12;
    if (ra < n) h[ra * 64 + c] = s0 * (dinv ? dinv[ra] : 1.f);
    if (rb < n) h[rb * 64 + c] = s1 * (dinv ? dinv[rb] : 1.f);
    if (rc2 < n) h[rc2 * 64 + c] = s2 * (dinv ? dinv[rc2] : 1.f);
    if (rd < n) h[rd * 64 + c] = s3 * (dinv ? dinv[rd] : 1.f);
}

// h2[n,40] = relu(agg)[n,64] @ W2[64,40] (* dinv[row] if dinv). 16 rows/block.
__global__ __launch_bounds__(320) void k_gemm2(const float* __restrict__ agg,
                                               const float* __restrict__ W2,
                                               float* __restrict__ h2, int n,
                                               const float* __restrict__ dinv) {
    __shared__ float Ws[64 * 40];
    __shared__ float hs[16 * 64];
    int tid = threadIdx.y * 40 + threadIdx.x;
    for (int i = tid; i < 64 * 40; i += 320) Ws[i] = W2[i];
    int row0 = blockIdx.x * 16;
    for (int i = tid; i < 16 * 64; i += 320) {
        int r = i >> 6, k = i & 63;
        int row = row0 + r;
        float v = (row < n) ? agg[row * 64 + k] : 0.0f;
        hs[i] = v > 0.0f ? v : 0.0f;
    }
    __syncthreads();
    int c = threadIdx.x, r = threadIdx.y;
    float s0 = 0.f, s1 = 0.f;
#pragma unroll
    for (int k = 0; k < 64; ++k) {
        float w = Ws[k * 40 + c];
        s0 += hs[r * 64 + k] * w;
        s1 += hs[(r + 8) * 64 + k] * w;
    }
    int ra = row0 + r, rb = ra + 8;
    if (ra < n) h2[ra * 40 + c] = s0 * (dinv ? dinv[ra] : 1.f);
    if (rb < n) h2[rb * 40 + c] = s1 * (dinv ? dinv[rb] : 1.f);
}

// ---------------- gathers (vectorized, no atomics) ----------------

#define F4ADD(a, b) { (a).x += (b).x; (a).y += (b).y; (a).z += (b).z; (a).w += (b).w; }

// agg[d] = (sum_{s in in(d)} hs[s] + hs[d]) * dinv[d] + b1, hs pre-scaled.
// Wave per node; lane -> (edge-group g = lane>>4, float4 index q = lane&15).
__global__ __launch_bounds__(256) void k_gather1(const float4* __restrict__ hs4,
                                                 const int* __restrict__ off,
                                                 const int* __restrict__ csrc,
                                                 const float* __restrict__ dinv,
                                                 const float4* __restrict__ b1_4,
                                                 float4* __restrict__ agg4, int n) {
    int node = blockIdx.x * 4 + (threadIdx.x >> 6);
    if (node >= n) return;
    int lane = threadIdx.x & 63;
    int g = lane >> 4, q = lane & 15;
    int beg = off[node], end = off[node + 1];
    float4 a0 = make_float4(0.f, 0.f, 0.f, 0.f);
    float4 a1 = make_float4(0.f, 0.f, 0.f, 0.f);
    int j = beg;
    for (; j + 8 <= end; j += 8) {
        int s0 = csrc[j + g];
        int s1 = csrc[j + 4 + g];
        float4 v0 = hs4[s0 * 16 + q];
        float4 v1 = hs4[s1 * 16 + q];
        F4ADD(a0, v0);
        F4ADD(a1, v1);
    }
    for (; j < end; j += 4) {
        int jj = j + g;
        if (jj < end) {
            int s = csrc[jj];
            float4 v = hs4[s * 16 + q];
            F4ADD(a0, v);
        }
    }
    F4ADD(a0, a1);
    a0.x += __shfl_down(a0.x, 32); a0.y += __shfl_down(a0.y, 32);
    a0.z += __shfl_down(a0.z, 32); a0.w += __shfl_down(a0.w, 32);
    a0.x += __shfl_down(a0.x, 16); a0.y += __shfl_down(a0.y, 16);
    a0.z += __shfl_down(a0.z, 16); a0.w += __shfl_down(a0.w, 16);
    if (lane < 16) {
        float dd = dinv[node];
        float4 s = hs4[node * 16 + q];
        float4 b = b1_4[q];
        float4 o;
        o.x = (a0.x + s.x) * dd + b.x;
        o.y = (a0.y + s.y) * dd + b.y;
        o.z = (a0.z + s.z) * dd + b.z;
        o.w = (a0.w + s.w) * dd + b.w;
        agg4[node * 16 + q] = o;
    }
}

// out[d] = (sum h2s[s] + h2s[d]) * dinv[d] + b2.  40 floats = 10 float4;
// 6 edge-groups of 10 lanes (lanes 60-63 idle).
__global__ __launch_bounds__(256) void k_gather2(const float4* __restrict__ h2s4,
                                                 const int* __restrict__ off,
                                                 const int* __restrict__ csrc,
                                                 const float* __restrict__ dinv,
                                                 const float4* __restrict__ b2_4,
                                                 float4* __restrict__ out4, int n) {
    int node = blockIdx.x * 4 + (threadIdx.x >> 6);
    if (node >= n) return;
    int lane = threadIdx.x & 63;
    int g = lane / 10;
    int q = lane - g * 10;
    bool act = g < 6;
    int beg = off[node], end = off[node + 1];
    float4 a0 = make_float4(0.f, 0.f, 0.f, 0.f);
    float4 a1 = make_float4(0.f, 0.f, 0.f, 0.f);
    int j = beg;
    for (; j + 12 <= end; j += 12) {
        if (act) {
            int s0 = csrc[j + g];
            int s1 = csrc[j + 6 + g];
            float4 v0 = h2s4[s0 * 10 + q];
            float4 v1 = h2s4[s1 * 10 + q];
            F4ADD(a0, v0);
            F4ADD(a1, v1);
        }
    }
    for (; j < end; j += 6) {
        int jj = j + g;
        if (act && jj < end) {
            int s = csrc[jj];
            float4 v = h2s4[s * 10 + q];
            F4ADD(a0, v);
        }
    }
    F4ADD(a0, a1);
    float4 r;
    r.x = __shfl_down(a0.x, 30); r.y = __shfl_down(a0.y, 30);
    r.z = __shfl_down(a0.z, 30); r.w = __shfl_down(a0.w, 30);
    if (lane < 30) F4ADD(a0, r);
    r.x = __shfl_down(a0.x, 20); r.y = __shfl_down(a0.y, 20);
    r.z = __shfl_down(a0.z, 20); r.w = __shfl_down(a0.w, 20);
    if (lane < 10) F4ADD(a0, r);
    r.x = __shfl_down(a0.x, 10); r.y = __shfl_down(a0.y, 10);
    r.z = __shfl_down(a0.z, 10); r.w = __shfl_down(a0.w, 10);
    if (lane < 10) F4ADD(a0, r);
    if (lane < 10) {
        float dd = dinv[node];
        float4 s = h2s4[node * 10 + q];
        float4 b = b2_4[q];
        float4 o;
        o.x = (a0.x + s.x) * dd + b.x;
        o.y = (a0.y + s.y) * dd + b.y;
        o.z = (a0.z + s.z) * dd + b.z;
        o.w = (a0.w + s.w) * dd + b.w;
        out4[node * 10 + q] = o;
    }
}

// ---------------- fallback atomic-scatter path ----------------

__global__ void k_init_deg(float* __restrict__ deg, int n) {
    int i = blockIdx.x * blockDim.x + threadIdx.x;
    if (i < n) deg[i] = 1.0f;
}

__global__ void k_deg(const int* __restrict__ dst, int E, float* __restrict__ deg) {
    int i = blockIdx.x * blockDim.x + threadIdx.x;
    if (i < E) atomicAdd(&deg[dst[i]], 1.0f);
}

__global__ void k_rsqrt(float* __restrict__ deg, int n) {
    int i = blockIdx.x * blockDim.x + threadIdx.x;
    if (i < n) deg[i] = rsqrtf(deg[i]);
}

__global__ void k_init_agg1(const float* __restrict__ h, const float* __restrict__ dinv,
                            const float* __restrict__ b1, float* __restrict__ agg, int n) {
    int idx = blockIdx.x * blockDim.x + threadIdx.x;
    if (idx < n * 64) {
        int i = idx >> 6, f = idx & 63;
        float d = dinv[i];
        agg[idx] = h[idx] * d * d + b1[f];
    }
}

__global__ __launch_bounds__(256) void k_scatter1(const float* __restrict__ h,
                                                  const int* __restrict__ src,
                                                  const int* __restrict__ dst,
                                                  const float* __restrict__ dinv,
                                                  float* __restrict__ agg, int E) {
    int e = blockIdx.x * 4 + (threadIdx.x >> 6);
    if (e >= E) return;
    int f = threadIdx.x & 63;
    int s = src[e], d = dst[e];
    float w = dinv[s] * dinv[d];
    atomicAdd(&agg[d * 64 + f], h[s * 64 + f] * w);
}

__global__ void k_init_out(const float* __restrict__ h2, const float* __restrict__ dinv,
                           const float* __restrict__ b2, float* __restrict__ out, int n) {
    int idx = blockIdx.x * blockDim.x + threadIdx.x;
    if (idx < n * 40) {
        int i = idx / 40;
        int f = idx - i * 40;
        float d = dinv[i];
        out[idx] = h2[idx] * d * d + b2[f];
    }
}

__global__ __launch_bounds__(256) void k_scatter2(const float* __restrict__ h2,
                                                  const int* __restrict__ src,
                                                  const int* __restrict__ dst,
                                                  const float* __restrict__ dinv,
                                                  float* __restrict__ out, int E) {
    int idx = blockIdx.x * blockDim.x + threadIdx.x;
    int total = E * 40;
    if (idx >= total) return;
    int e = idx / 40;
    int f = idx - e * 40;
    int s = src[e], d = dst[e];
    float w = dinv[s] * dinv[d];
    atomicAdd(&out[d * 40 + f], h2[s * 40 + f] * w);
}

extern "C" void kernel_launch(void* const* d_in, const int* in_sizes, int n_in,
                              void* d_out, int out_size, void* d_ws, size_t ws_size,
                              hipStream_t stream) {
    const float* x  = (const float*)d_in[0];
    const int*   ei = (const int*)d_in[1];
    const float* W1 = (const float*)d_in[2];
    const float* b1 = (const float*)d_in[3];
    const float* W2 = (const float*)d_in[4];
    const float* b2 = (const float*)d_in[5];
    float* out = (float*)d_out;

    const int n = in_sizes[0] / 128;   // 100000
    const int E = in_sizes[1] / 2;     // 1600000
    const int* src = ei;
    const int* dst = ei + E;

    char* ws = (char*)d_ws;
    const size_t MB = 1 << 20;
    float* dinv  = (float*)(ws);                       // n floats
    int*   off   = (int*)  (ws + 512 * 1024);          // n+1 ints
    int*   bcnt  = (int*)  (ws + 1 * MB);              // NBCAP ints
    int*   bbase = (int*)  (ws + 1 * MB + 8 * 1024);   // NBCAP+1 ints
    int*   bcur  = (int*)  (ws + 1 * MB + 16 * 1024);  // NBCAP ints
    float* hs    = (float*)(ws + 2 * MB);              // n*64 (25.6MB), reused for h2s
    float* agg1  = (float*)(ws + 28 * MB);             // n*64 (25.6MB)
    int*   pairs = (int*)  (ws + 28 * MB);             // E ints, consumed before agg1 written
    int*   csrc  = (int*)  (ws + 54 * MB);             // E ints
    size_t needed = 54 * MB + (size_t)E * 4;

    const int nb = (n + NPB - 1) / NPB;

    if (ws_size >= needed && nb <= NBCAP && n <= (1 << 17)) {
        // ---- CSC build via counting sort ----
        k_zero<<<(nb + 255) / 256, 256, 0, stream>>>(bcnt, nb);
        k_hist<<<512, 256, 0, stream>>>(dst, E, bcnt, nb);
        k_scan_nb<<<1, 1024, 0, stream>>>(bcnt, bbase, bcur, nb);
        k_binpass<<<(E + 4095) / 4096, 256, 0, stream>>>(src, dst, bcur, pairs, nb, E);
        k_bucket_build<<<nb, 256, 0, stream>>>(pairs, bbase, off, csrc, dinv, n, nb);

        // ---- layer 1 ----
        k_gemm1<<<(n + 15) / 16, 256, 0, stream>>>(x, W1, hs, n, dinv);
        k_gather1<<<(n + 3) / 4, 256, 0, stream>>>((const float4*)hs, off, csrc, dinv,
                                                   (const float4*)b1, (float4*)agg1, n);
        // ---- layer 2 ----
        dim3 blk2(40, 8);
        k_gemm2<<<(n + 15) / 16, blk2, 0, stream>>>(agg1, W2, hs, n, dinv);
        k_gather2<<<(n + 3) / 4, 256, 0, stream>>>((const float4*)hs, off, csrc, dinv,
                                                   (const float4*)b2, (float4*)out, n);
    } else {
        // ---- fallback: atomic scatter path ----
        float* hlin = hs;
        k_init_deg<<<(n + 255) / 256, 256, 0, stream>>>(dinv, n);
        k_deg<<<(E + 255) / 256, 256, 0, stream>>>(dst, E, dinv);
        k_rsqrt<<<(n + 255) / 256, 256, 0, stream>>>(dinv, n);
        k_gemm1<<<(n + 15) / 16, 256, 0, stream>>>(x, W1, hlin, n, nullptr);
        k_init_agg1<<<(n * 64 + 255) / 256, 256, 0, stream>>>(hlin, dinv, b1, agg1, n);
        k_scatter1<<<(E + 3) / 4, 256, 0, stream>>>(hlin, src, dst, dinv, agg1, E);
        dim3 blk2(40, 8);
        k_gemm2<<<(n + 15) / 16, blk2, 0, stream>>>(agg1, W2, hlin, n, nullptr);
        k_init_out<<<(n * 40 + 255) / 256, 256, 0, stream>>>(hlin, dinv, b2, out, n);
        int total2 = E * 40;
        k_scatter2<<<(total2 + 255) / 256, 256, 0, stream>>>(hlin, src, dst, dinv, out, E);
    }
}

// Round 4
// 233.350 us; speedup vs baseline: 3.7203x; 1.3602x over previous
//
#include <hip/hip_runtime.h>

// ---------------------------------------------------------------------------
// GCN 2-layer forward: out = A_hat @ relu(A_hat @ (x@W1) + b1) @ W2 + b2
// A_hat = D^-1/2 (A + I) D^-1/2.
// CSC via locality-aware counting sort; gathers vectorized float4;
// GEMMs register-tiled 4x4 outer-product with transposed-LDS staging.
// ---------------------------------------------------------------------------

#define NPB   128     // nodes per coarse bucket
#define NBCAP 1024    // max buckets supported by fast path

// ---------------- CSC build ----------------

__global__ void k_zero(int* __restrict__ p, int m) {
    int i = blockIdx.x * blockDim.x + threadIdx.x;
    if (i < m) p[i] = 0;
}

__global__ __launch_bounds__(256) void k_hist(const int* __restrict__ dst, int E,
                                              int* __restrict__ bcnt, int nb) {
    __shared__ int h[NBCAP];
    for (int i = threadIdx.x; i < nb; i += 256) h[i] = 0;
    __syncthreads();
    int stride = gridDim.x * 256;
    for (int e = blockIdx.x * 256 + threadIdx.x; e < E; e += stride)
        atomicAdd(&h[dst[e] >> 7], 1);
    __syncthreads();
    for (int i = threadIdx.x; i < nb; i += 256)
        if (h[i]) atomicAdd(&bcnt[i], h[i]);
}

__global__ __launch_bounds__(1024) void k_scan_nb(const int* __restrict__ bcnt,
                                                  int* __restrict__ bbase,
                                                  int* __restrict__ bcur, int nb) {
    __shared__ int tmp[NBCAP];
    int t = threadIdx.x;
    int v = (t < nb) ? bcnt[t] : 0;
    tmp[t] = v;
    __syncthreads();
    for (int ofs = 1; ofs < NBCAP; ofs <<= 1) {
        int u = (t >= ofs) ? tmp[t - ofs] : 0;
        __syncthreads();
        if (t >= ofs) tmp[t] += u;
        __syncthreads();
    }
    if (t < nb) {
        int ex = tmp[t] - v;
        bbase[t] = ex;
        bcur[t] = ex;
        if (t == nb - 1) bbase[nb] = tmp[t];
    }
}

// Each block: 4096 edges stashed in registers; LDS hist; one global atomic
// per (block,bucket) to reserve; LDS-cursor scatter of packed src|ldst.
__global__ __launch_bounds__(256) void k_binpass(const int* __restrict__ src,
                                                 const int* __restrict__ dst,
                                                 int* __restrict__ bcur,
                                                 int* __restrict__ pairs,
                                                 int nb, int E) {
    __shared__ int lh[NBCAP];
    __shared__ int lbase[NBCAP];
    for (int i = threadIdx.x; i < nb; i += 256) lh[i] = 0;
    __syncthreads();
    int base = blockIdx.x * 4096;
    int pk[16], bb[16];
#pragma unroll
    for (int k = 0; k < 16; ++k) {
        int e = base + k * 256 + threadIdx.x;
        if (e < E) {
            int d = dst[e];
            int b = d >> 7;
            bb[k] = b;
            pk[k] = src[e] | ((d & (NPB - 1)) << 17);
            atomicAdd(&lh[b], 1);
        } else bb[k] = -1;
    }
    __syncthreads();
    for (int i = threadIdx.x; i < nb; i += 256) {
        int c = lh[i];
        lbase[i] = c ? atomicAdd(&bcur[i], c) : 0;
        lh[i] = 0;
    }
    __syncthreads();
#pragma unroll
    for (int k = 0; k < 16; ++k) {
        if (bb[k] >= 0) {
            int r = atomicAdd(&lh[bb[k]], 1);
            pairs[lbase[bb[k]] + r] = pk[k];
        }
    }
}

// One block per bucket: LDS degree count + scan -> off/dinv; LDS-cursor fill
// of csrc confined to an ~8KB region (L2-merged writes).
__global__ __launch_bounds__(256) void k_bucket_build(const int* __restrict__ pairs,
                                                      const int* __restrict__ bbase,
                                                      int* __restrict__ off,
                                                      int* __restrict__ csrc,
                                                      float* __restrict__ dinv,
                                                      int n, int nb) {
    __shared__ int deg[NPB], sc[NPB], cur[NPB];
    int t = threadIdx.x;
    int bid = blockIdx.x;
    int node0 = bid * NPB;
    int ebeg = bbase[bid], eend = bbase[bid + 1];
    if (t < NPB) deg[t] = 0;
    __syncthreads();
    for (int e = ebeg + t; e < eend; e += 256)
        atomicAdd(&deg[pairs[e] >> 17], 1);
    __syncthreads();
    if (t < NPB) sc[t] = deg[t];
    __syncthreads();
    for (int ofs = 1; ofs < NPB; ofs <<= 1) {
        int u = (t < NPB && t >= ofs) ? sc[t - ofs] : 0;
        __syncthreads();
        if (t < NPB && t >= ofs) sc[t] += u;
        __syncthreads();
    }
    if (t < NPB) {
        int ex = sc[t] - deg[t];
        cur[t] = ex;
        int node = node0 + t;
        if (node < n) {
            off[node] = ebeg + ex;
            dinv[node] = rsqrtf((float)(deg[t] + 1));
        }
    }
    if (t == 0 && bid == nb - 1) off[n] = eend;
    __syncthreads();
    for (int e = ebeg + t; e < eend; e += 256) {
        int pkv = pairs[e];
        int r = atomicAdd(&cur[pkv >> 17], 1);
        csrc[ebeg + r] = pkv & 0x1FFFF;
    }
}

// ---------------- dense layers: register-tiled outer product ----------------

// h[n,64] = (x[n,128] @ W[128,64]) * dinv[row]. 64 rows/block, 256 thr,
// 4x4 tile/thread. xsT[k][row] (transposed) + Ws[k][col], b128 LDS reads.
__global__ __launch_bounds__(256) void k_gemm1(const float* __restrict__ x,
                                               const float* __restrict__ W,
                                               float* __restrict__ h, int n,
                                               const float* __restrict__ dinv) {
    __shared__ float Ws[128 * 64];    // 32 KB, [k][c]
    __shared__ float xsT[128 * 64];   // 32 KB, [k][r]
    const int tid = threadIdx.x;
    const int row0 = blockIdx.x * 64;

    // stage W (direct copy, coalesced float4)
    {
        const float4* Wg = (const float4*)W;
        float4* Wl = (float4*)Ws;
#pragma unroll
        for (int t = 0; t < 8; ++t) Wl[tid + t * 256] = Wg[tid + t * 256];
    }
    // stage x transposed: lane r = tid&63 owns row (row0+r), group g = tid>>6
    {
        int r = tid & 63, g = tid >> 6;
        int row = row0 + r;
        const float4* xr = (const float4*)(x + (size_t)row * 128);
#pragma unroll
        for (int t = 0; t < 8; ++t) {
            int k0 = g * 32 + t * 4;
            float4 v = (row < n) ? xr[k0 >> 2] : make_float4(0.f, 0.f, 0.f, 0.f);
            xsT[(k0 + 0) * 64 + r] = v.x;
            xsT[(k0 + 1) * 64 + r] = v.y;
            xsT[(k0 + 2) * 64 + r] = v.z;
            xsT[(k0 + 3) * 64 + r] = v.w;
        }
    }
    __syncthreads();

    const int tc = tid & 15;    // col group: cols tc*4..tc*4+3
    const int rg = tid >> 4;    // row group: rows rg*4..rg*4+3
    float acc[4][4];
#pragma unroll
    for (int i = 0; i < 4; ++i)
#pragma unroll
        for (int j = 0; j < 4; ++j) acc[i][j] = 0.f;

#pragma unroll 4
    for (int k = 0; k < 128; ++k) {
        float4 a = *(const float4*)&xsT[k * 64 + rg * 4];
        float4 b = *(const float4*)&Ws[k * 64 + tc * 4];
        acc[0][0] += a.x * b.x; acc[0][1] += a.x * b.y; acc[0][2] += a.x * b.z; acc[0][3] += a.x * b.w;
        acc[1][0] += a.y * b.x; acc[1][1] += a.y * b.y; acc[1][2] += a.y * b.z; acc[1][3] += a.y * b.w;
        acc[2][0] += a.z * b.x; acc[2][1] += a.z * b.y; acc[2][2] += a.z * b.z; acc[2][3] += a.z * b.w;
        acc[3][0] += a.w * b.x; acc[3][1] += a.w * b.y; acc[3][2] += a.w * b.z; acc[3][3] += a.w * b.w;
    }

#pragma unroll
    for (int i = 0; i < 4; ++i) {
        int row = row0 + rg * 4 + i;
        if (row < n) {
            float dd = dinv ? dinv[row] : 1.f;
            float4 o = make_float4(acc[i][0] * dd, acc[i][1] * dd, acc[i][2] * dd, acc[i][3] * dd);
            *(float4*)&h[(size_t)row * 64 + tc * 4] = o;
        }
    }
}

// h2[n,40] = (relu(agg[n,64]) @ W2[64,40]) * dinv[row]. 64 rows/block,
// 256 thr (160 compute), 4x4 tile. hsT[k][r] + Ws2[k][c] (stride 40).
__global__ __launch_bounds__(256) void k_gemm2(const float* __restrict__ agg,
                                               const float* __restrict__ W2,
                                               float* __restrict__ h2, int n,
                                               const float* __restrict__ dinv) {
    __shared__ float Ws[64 * 40];     // 10.24 KB, [k][c]
    __shared__ float hsT[64 * 64];    // 16 KB, [k][r]
    const int tid = threadIdx.x;
    const int row0 = blockIdx.x * 64;

    // stage W2 (640 float4 = 2560 floats), coalesced
    {
        const float4* Wg = (const float4*)W2;
        float4* Wl = (float4*)Ws;
        for (int i = tid; i < 640; i += 256) Wl[i] = Wg[i];
    }
    // stage agg transposed with fused relu
    {
        int r = tid & 63, g = tid >> 6;
        int row = row0 + r;
        const float4* ar = (const float4*)(agg + (size_t)row * 64);
#pragma unroll
        for (int t = 0; t < 4; ++t) {
            int k0 = g * 16 + t * 4;
            float4 v = (row < n) ? ar[k0 >> 2] : make_float4(0.f, 0.f, 0.f, 0.f);
            hsT[(k0 + 0) * 64 + r] = v.x > 0.f ? v.x : 0.f;
            hsT[(k0 + 1) * 64 + r] = v.y > 0.f ? v.y : 0.f;
            hsT[(k0 + 2) * 64 + r] = v.z > 0.f ? v.z : 0.f;
            hsT[(k0 + 3) * 64 + r] = v.w > 0.f ? v.w : 0.f;
        }
    }
    __syncthreads();

    const int tc = tid & 15;    // col group; only tc<10 compute (cols tc*4..+3)
    const int rg = tid >> 4;    // row group
    if (tc < 10) {
        float acc[4][4];
#pragma unroll
        for (int i = 0; i < 4; ++i)
#pragma unroll
            for (int j = 0; j < 4; ++j) acc[i][j] = 0.f;

#pragma unroll 4
        for (int k = 0; k < 64; ++k) {
            float4 a = *(const float4*)&hsT[k * 64 + rg * 4];
            float4 b = *(const float4*)&Ws[k * 40 + tc * 4];
            acc[0][0] += a.x * b.x; acc[0][1] += a.x * b.y; acc[0][2] += a.x * b.z; acc[0][3] += a.x * b.w;
            acc[1][0] += a.y * b.x; acc[1][1] += a.y * b.y; acc[1][2] += a.y * b.z; acc[1][3] += a.y * b.w;
            acc[2][0] += a.z * b.x; acc[2][1] += a.z * b.y; acc[2][2] += a.z * b.z; acc[2][3] += a.z * b.w;
            acc[3][0] += a.w * b.x; acc[3][1] += a.w * b.y; acc[3][2] += a.w * b.z; acc[3][3] += a.w * b.w;
        }

#pragma unroll
        for (int i = 0; i < 4; ++i) {
            int row = row0 + rg * 4 + i;
            if (row < n) {
                float dd = dinv ? dinv[row] : 1.f;
                float4 o = make_float4(acc[i][0] * dd, acc[i][1] * dd, acc[i][2] * dd, acc[i][3] * dd);
                *(float4*)&h2[(size_t)row * 40 + tc * 4] = o;
            }
        }
    }
}

// ---------------- gathers (vectorized, no atomics) ----------------

#define F4ADD(a, b) { (a).x += (b).x; (a).y += (b).y; (a).z += (b).z; (a).w += (b).w; }

// agg[d] = (sum_{s in in(d)} hs[s] + hs[d]) * dinv[d] + b1, hs pre-scaled.
__global__ __launch_bounds__(256) void k_gather1(const float4* __restrict__ hs4,
                                                 const int* __restrict__ off,
                                                 const int* __restrict__ csrc,
                                                 const float* __restrict__ dinv,
                                                 const float4* __restrict__ b1_4,
                                                 float4* __restrict__ agg4, int n) {
    int node = blockIdx.x * 4 + (threadIdx.x >> 6);
    if (node >= n) return;
    int lane = threadIdx.x & 63;
    int g = lane >> 4, q = lane & 15;
    int beg = off[node], end = off[node + 1];
    float4 a0 = make_float4(0.f, 0.f, 0.f, 0.f);
    float4 a1 = make_float4(0.f, 0.f, 0.f, 0.f);
    int j = beg;
    for (; j + 8 <= end; j += 8) {
        int s0 = csrc[j + g];
        int s1 = csrc[j + 4 + g];
        float4 v0 = hs4[s0 * 16 + q];
        float4 v1 = hs4[s1 * 16 + q];
        F4ADD(a0, v0);
        F4ADD(a1, v1);
    }
    for (; j < end; j += 4) {
        int jj = j + g;
        if (jj < end) {
            int s = csrc[jj];
            float4 v = hs4[s * 16 + q];
            F4ADD(a0, v);
        }
    }
    F4ADD(a0, a1);
    a0.x += __shfl_down(a0.x, 32); a0.y += __shfl_down(a0.y, 32);
    a0.z += __shfl_down(a0.z, 32); a0.w += __shfl_down(a0.w, 32);
    a0.x += __shfl_down(a0.x, 16); a0.y += __shfl_down(a0.y, 16);
    a0.z += __shfl_down(a0.z, 16); a0.w += __shfl_down(a0.w, 16);
    if (lane < 16) {
        float dd = dinv[node];
        float4 s = hs4[node * 16 + q];
        float4 b = b1_4[q];
        float4 o;
        o.x = (a0.x + s.x) * dd + b.x;
        o.y = (a0.y + s.y) * dd + b.y;
        o.z = (a0.z + s.z) * dd + b.z;
        o.w = (a0.w + s.w) * dd + b.w;
        agg4[node * 16 + q] = o;
    }
}

// out[d] = (sum h2s[s] + h2s[d]) * dinv[d] + b2.  40 floats = 10 float4.
__global__ __launch_bounds__(256) void k_gather2(const float4* __restrict__ h2s4,
                                                 const int* __restrict__ off,
                                                 const int* __restrict__ csrc,
                                                 const float* __restrict__ dinv,
                                                 const float4* __restrict__ b2_4,
                                                 float4* __restrict__ out4, int n) {
    int node = blockIdx.x * 4 + (threadIdx.x >> 6);
    if (node >= n) return;
    int lane = threadIdx.x & 63;
    int g = lane / 10;
    int q = lane - g * 10;
    bool act = g < 6;
    int beg = off[node], end = off[node + 1];
    float4 a0 = make_float4(0.f, 0.f, 0.f, 0.f);
    float4 a1 = make_float4(0.f, 0.f, 0.f, 0.f);
    int j = beg;
    for (; j + 12 <= end; j += 12) {
        if (act) {
            int s0 = csrc[j + g];
            int s1 = csrc[j + 6 + g];
            float4 v0 = h2s4[s0 * 10 + q];
            float4 v1 = h2s4[s1 * 10 + q];
            F4ADD(a0, v0);
            F4ADD(a1, v1);
        }
    }
    for (; j < end; j += 6) {
        int jj = j + g;
        if (act && jj < end) {
            int s = csrc[jj];
            float4 v = h2s4[s * 10 + q];
            F4ADD(a0, v);
        }
    }
    F4ADD(a0, a1);
    float4 r;
    r.x = __shfl_down(a0.x, 30); r.y = __shfl_down(a0.y, 30);
    r.z = __shfl_down(a0.z, 30); r.w = __shfl_down(a0.w, 30);
    if (lane < 30) F4ADD(a0, r);
    r.x = __shfl_down(a0.x, 20); r.y = __shfl_down(a0.y, 20);
    r.z = __shfl_down(a0.z, 20); r.w = __shfl_down(a0.w, 20);
    if (lane < 10) F4ADD(a0, r);
    r.x = __shfl_down(a0.x, 10); r.y = __shfl_down(a0.y, 10);
    r.z = __shfl_down(a0.z, 10); r.w = __shfl_down(a0.w, 10);
    if (lane < 10) F4ADD(a0, r);
    if (lane < 10) {
        float dd = dinv[node];
        float4 s = h2s4[node * 10 + q];
        float4 b = b2_4[q];
        float4 o;
        o.x = (a0.x + s.x) * dd + b.x;
        o.y = (a0.y + s.y) * dd + b.y;
        o.z = (a0.z + s.z) * dd + b.z;
        o.w = (a0.w + s.w) * dd + b.w;
        out4[node * 10 + q] = o;
    }
}

// ---------------- fallback atomic-scatter path ----------------

__global__ void k_init_deg(float* __restrict__ deg, int n) {
    int i = blockIdx.x * blockDim.x + threadIdx.x;
    if (i < n) deg[i] = 1.0f;
}

__global__ void k_deg(const int* __restrict__ dst, int E, float* __restrict__ deg) {
    int i = blockIdx.x * blockDim.x + threadIdx.x;
    if (i < E) atomicAdd(&deg[dst[i]], 1.0f);
}

__global__ void k_rsqrt(float* __restrict__ deg, int n) {
    int i = blockIdx.x * blockDim.x + threadIdx.x;
    if (i < n) deg[i] = rsqrtf(deg[i]);
}

__global__ void k_init_agg1(const float* __restrict__ h, const float* __restrict__ dinv,
                            const float* __restrict__ b1, float* __restrict__ agg, int n) {
    int idx = blockIdx.x * blockDim.x + threadIdx.x;
    if (idx < n * 64) {
        int i = idx >> 6, f = idx & 63;
        float d = dinv[i];
        agg[idx] = h[idx] * d * d + b1[f];
    }
}

__global__ __launch_bounds__(256) void k_scatter1(const float* __restrict__ h,
                                                  const int* __restrict__ src,
                                                  const int* __restrict__ dst,
                                                  const float* __restrict__ dinv,
                                                  float* __restrict__ agg, int E) {
    int e = blockIdx.x * 4 + (threadIdx.x >> 6);
    if (e >= E) return;
    int f = threadIdx.x & 63;
    int s = src[e], d = dst[e];
    float w = dinv[s] * dinv[d];
    atomicAdd(&agg[d * 64 + f], h[s * 64 + f] * w);
}

__global__ void k_init_out(const float* __restrict__ h2, const float* __restrict__ dinv,
                           const float* __restrict__ b2, float* __restrict__ out, int n) {
    int idx = blockIdx.x * blockDim.x + threadIdx.x;
    if (idx < n * 40) {
        int i = idx / 40;
        int f = idx - i * 40;
        float d = dinv[i];
        out[idx] = h2[idx] * d * d + b2[f];
    }
}

__global__ __launch_bounds__(256) void k_scatter2(const float* __restrict__ h2,
                                                  const int* __restrict__ src,
                                                  const int* __restrict__ dst,
                                                  const float* __restrict__ dinv,
                                                  float* __restrict__ out, int E) {
    int idx = blockIdx.x * blockDim.x + threadIdx.x;
    int total = E * 40;
    if (idx >= total) return;
    int e = idx / 40;
    int f = idx - e * 40;
    int s = src[e], d = dst[e];
    float w = dinv[s] * dinv[d];
    atomicAdd(&out[d * 40 + f], h2[s * 40 + f] * w);
}

extern "C" void kernel_launch(void* const* d_in, const int* in_sizes, int n_in,
                              void* d_out, int out_size, void* d_ws, size_t ws_size,
                              hipStream_t stream) {
    const float* x  = (const float*)d_in[0];
    const int*   ei = (const int*)d_in[1];
    const float* W1 = (const float*)d_in[2];
    const float* b1 = (const float*)d_in[3];
    const float* W2 = (const float*)d_in[4];
    const float* b2 = (const float*)d_in[5];
    float* out = (float*)d_out;

    const int n = in_sizes[0] / 128;   // 100000
    const int E = in_sizes[1] / 2;     // 1600000
    const int* src = ei;
    const int* dst = ei + E;

    char* ws = (char*)d_ws;
    const size_t MB = 1 << 20;
    float* dinv  = (float*)(ws);                       // n floats
    int*   off   = (int*)  (ws + 512 * 1024);          // n+1 ints
    int*   bcnt  = (int*)  (ws + 1 * MB);              // NBCAP ints
    int*   bbase = (int*)  (ws + 1 * MB + 8 * 1024);   // NBCAP+1 ints
    int*   bcur  = (int*)  (ws + 1 * MB + 16 * 1024);  // NBCAP ints
    float* hs    = (float*)(ws + 2 * MB);              // n*64 (25.6MB), reused for h2s
    float* agg1  = (float*)(ws + 28 * MB);             // n*64 (25.6MB)
    int*   pairs = (int*)  (ws + 28 * MB);             // E ints, consumed before agg1 written
    int*   csrc  = (int*)  (ws + 54 * MB);             // E ints
    size_t needed = 54 * MB + (size_t)E * 4;

    const int nb = (n + NPB - 1) / NPB;

    if (ws_size >= needed && nb <= NBCAP && n <= (1 << 17)) {
        // ---- CSC build via counting sort ----
        k_zero<<<(nb + 255) / 256, 256, 0, stream>>>(bcnt, nb);
        k_hist<<<512, 256, 0, stream>>>(dst, E, bcnt, nb);
        k_scan_nb<<<1, 1024, 0, stream>>>(bcnt, bbase, bcur, nb);
        k_binpass<<<(E + 4095) / 4096, 256, 0, stream>>>(src, dst, bcur, pairs, nb, E);
        k_bucket_build<<<nb, 256, 0, stream>>>(pairs, bbase, off, csrc, dinv, n, nb);

        // ---- layer 1 ----
        k_gemm1<<<(n + 63) / 64, 256, 0, stream>>>(x, W1, hs, n, dinv);
        k_gather1<<<(n + 3) / 4, 256, 0, stream>>>((const float4*)hs, off, csrc, dinv,
                                                   (const float4*)b1, (float4*)agg1, n);
        // ---- layer 2 ----
        k_gemm2<<<(n + 63) / 64, 256, 0, stream>>>(agg1, W2, hs, n, dinv);
        k_gather2<<<(n + 3) / 4, 256, 0, stream>>>((const float4*)hs, off, csrc, dinv,
                                                   (const float4*)b2, (float4*)out, n);
    } else {
        // ---- fallback: atomic scatter path ----
        float* hlin = hs;
        k_init_deg<<<(n + 255) / 256, 256, 0, stream>>>(dinv, n);
        k_deg<<<(E + 255) / 256, 256, 0, stream>>>(dst, E, dinv);
        k_rsqrt<<<(n + 255) / 256, 256, 0, stream>>>(dinv, n);
        k_gemm1<<<(n + 63) / 64, 256, 0, stream>>>(x, W1, hlin, n, nullptr);
        k_init_agg1<<<(n * 64 + 255) / 256, 256, 0, stream>>>(hlin, dinv, b1, agg1, n);
        k_scatter1<<<(E + 3) / 4, 256, 0, stream>>>(hlin, src, dst, dinv, agg1, E);
        k_gemm2<<<(n + 63) / 64, 256, 0, stream>>>(agg1, W2, hlin, n, nullptr);
        k_init_out<<<(n * 40 + 255) / 256, 256, 0, stream>>>(hlin, dinv, b2, out, n);
        int total2 = E * 40;
        k_scatter2<<<(total2 + 255) / 256, 256, 0, stream>>>(hlin, src, dst, dinv, out, E);
    }
}

// Round 5
// 208.367 us; speedup vs baseline: 4.1663x; 1.1199x over previous
//
#include <hip/hip_runtime.h>
#include <hip/hip_fp16.h>

// ---------------------------------------------------------------------------
// GCN 2-layer forward: out = A_hat @ relu(A_hat @ (x@W1) + b1) @ W2 + b2
// A_hat = D^-1/2 (A + I) D^-1/2.
// CSC via locality-aware counting sort; gathers vectorized, intermediates
// (hs, agg1, h2s) stored fp16 to halve random-gather traffic; fp32 compute.
// ---------------------------------------------------------------------------

#define NPB   128     // nodes per coarse bucket
#define NBCAP 1024    // max buckets supported by fast path

// ---------------- CSC build ----------------

__global__ void k_zero(int* __restrict__ p, int m) {
    int i = blockIdx.x * blockDim.x + threadIdx.x;
    if (i < m) p[i] = 0;
}

__global__ __launch_bounds__(256) void k_hist(const int* __restrict__ dst, int E,
                                              int* __restrict__ bcnt, int nb) {
    __shared__ int h[NBCAP];
    for (int i = threadIdx.x; i < nb; i += 256) h[i] = 0;
    __syncthreads();
    int stride = gridDim.x * 256;
    for (int e = blockIdx.x * 256 + threadIdx.x; e < E; e += stride)
        atomicAdd(&h[dst[e] >> 7], 1);
    __syncthreads();
    for (int i = threadIdx.x; i < nb; i += 256)
        if (h[i]) atomicAdd(&bcnt[i], h[i]);
}

__global__ __launch_bounds__(1024) void k_scan_nb(const int* __restrict__ bcnt,
                                                  int* __restrict__ bbase,
                                                  int* __restrict__ bcur, int nb) {
    __shared__ int tmp[NBCAP];
    int t = threadIdx.x;
    int v = (t < nb) ? bcnt[t] : 0;
    tmp[t] = v;
    __syncthreads();
    for (int ofs = 1; ofs < NBCAP; ofs <<= 1) {
        int u = (t >= ofs) ? tmp[t - ofs] : 0;
        __syncthreads();
        if (t >= ofs) tmp[t] += u;
        __syncthreads();
    }
    if (t < nb) {
        int ex = tmp[t] - v;
        bbase[t] = ex;
        bcur[t] = ex;
        if (t == nb - 1) bbase[nb] = tmp[t];
    }
}

__global__ __launch_bounds__(256) void k_binpass(const int* __restrict__ src,
                                                 const int* __restrict__ dst,
                                                 int* __restrict__ bcur,
                                                 int* __restrict__ pairs,
                                                 int nb, int E) {
    __shared__ int lh[NBCAP];
    __shared__ int lbase[NBCAP];
    for (int i = threadIdx.x; i < nb; i += 256) lh[i] = 0;
    __syncthreads();
    int base = blockIdx.x * 4096;
    int pk[16], bb[16];
#pragma unroll
    for (int k = 0; k < 16; ++k) {
        int e = base + k * 256 + threadIdx.x;
        if (e < E) {
            int d = dst[e];
            int b = d >> 7;
            bb[k] = b;
            pk[k] = src[e] | ((d & (NPB - 1)) << 17);
            atomicAdd(&lh[b], 1);
        } else bb[k] = -1;
    }
    __syncthreads();
    for (int i = threadIdx.x; i < nb; i += 256) {
        int c = lh[i];
        lbase[i] = c ? atomicAdd(&bcur[i], c) : 0;
        lh[i] = 0;
    }
    __syncthreads();
#pragma unroll
    for (int k = 0; k < 16; ++k) {
        if (bb[k] >= 0) {
            int r = atomicAdd(&lh[bb[k]], 1);
            pairs[lbase[bb[k]] + r] = pk[k];
        }
    }
}

__global__ __launch_bounds__(256) void k_bucket_build(const int* __restrict__ pairs,
                                                      const int* __restrict__ bbase,
                                                      int* __restrict__ off,
                                                      int* __restrict__ csrc,
                                                      float* __restrict__ dinv,
                                                      int n, int nb) {
    __shared__ int deg[NPB], sc[NPB], cur[NPB];
    int t = threadIdx.x;
    int bid = blockIdx.x;
    int node0 = bid * NPB;
    int ebeg = bbase[bid], eend = bbase[bid + 1];
    if (t < NPB) deg[t] = 0;
    __syncthreads();
    for (int e = ebeg + t; e < eend; e += 256)
        atomicAdd(&deg[pairs[e] >> 17], 1);
    __syncthreads();
    if (t < NPB) sc[t] = deg[t];
    __syncthreads();
    for (int ofs = 1; ofs < NPB; ofs <<= 1) {
        int u = (t < NPB && t >= ofs) ? sc[t - ofs] : 0;
        __syncthreads();
        if (t < NPB && t >= ofs) sc[t] += u;
        __syncthreads();
    }
    if (t < NPB) {
        int ex = sc[t] - deg[t];
        cur[t] = ex;
        int node = node0 + t;
        if (node < n) {
            off[node] = ebeg + ex;
            dinv[node] = rsqrtf((float)(deg[t] + 1));
        }
    }
    if (t == 0 && bid == nb - 1) off[n] = eend;
    __syncthreads();
    for (int e = ebeg + t; e < eend; e += 256) {
        int pkv = pairs[e];
        int r = atomicAdd(&cur[pkv >> 17], 1);
        csrc[ebeg + r] = pkv & 0x1FFFF;
    }
}

// ---------------- helpers ----------------

union pk2 { __half2 h[2]; uint2 u; };

__device__ __forceinline__ void h4_acc(const __half* p, float4& a) {
    uint2 u = *(const uint2*)p;
    __half2 h0 = *(__half2*)&u.x, h1 = *(__half2*)&u.y;
    float2 f0 = __half22float2(h0), f1 = __half22float2(h1);
    a.x += f0.x; a.y += f0.y; a.z += f1.x; a.w += f1.y;
}

#define F4ADD(a, b) { (a).x += (b).x; (a).y += (b).y; (a).z += (b).z; (a).w += (b).w; }

// ---------------- dense layers (fp16 out, register-tiled) ----------------

// hs[n,64] = (x[n,128] @ W[128,64]) * dinv[row], fp16 out.
__global__ __launch_bounds__(256) void k_gemm1_h(const float* __restrict__ x,
                                                 const float* __restrict__ W,
                                                 __half* __restrict__ h, int n,
                                                 const float* __restrict__ dinv) {
    __shared__ float Ws[128 * 64];
    __shared__ float xsT[128 * 64];
    const int tid = threadIdx.x;
    const int row0 = blockIdx.x * 64;
    {
        const float4* Wg = (const float4*)W;
        float4* Wl = (float4*)Ws;
#pragma unroll
        for (int t = 0; t < 8; ++t) Wl[tid + t * 256] = Wg[tid + t * 256];
    }
    {
        int r = tid & 63, g = tid >> 6;
        int row = row0 + r;
        const float4* xr = (const float4*)(x + (size_t)row * 128);
#pragma unroll
        for (int t = 0; t < 8; ++t) {
            int k0 = g * 32 + t * 4;
            float4 v = (row < n) ? xr[k0 >> 2] : make_float4(0.f, 0.f, 0.f, 0.f);
            xsT[(k0 + 0) * 64 + r] = v.x;
            xsT[(k0 + 1) * 64 + r] = v.y;
            xsT[(k0 + 2) * 64 + r] = v.z;
            xsT[(k0 + 3) * 64 + r] = v.w;
        }
    }
    __syncthreads();

    const int tc = tid & 15;
    const int rg = tid >> 4;
    float acc[4][4];
#pragma unroll
    for (int i = 0; i < 4; ++i)
#pragma unroll
        for (int j = 0; j < 4; ++j) acc[i][j] = 0.f;

#pragma unroll 4
    for (int k = 0; k < 128; ++k) {
        float4 a = *(const float4*)&xsT[k * 64 + rg * 4];
        float4 b = *(const float4*)&Ws[k * 64 + tc * 4];
        acc[0][0] += a.x * b.x; acc[0][1] += a.x * b.y; acc[0][2] += a.x * b.z; acc[0][3] += a.x * b.w;
        acc[1][0] += a.y * b.x; acc[1][1] += a.y * b.y; acc[1][2] += a.y * b.z; acc[1][3] += a.y * b.w;
        acc[2][0] += a.z * b.x; acc[2][1] += a.z * b.y; acc[2][2] += a.z * b.z; acc[2][3] += a.z * b.w;
        acc[3][0] += a.w * b.x; acc[3][1] += a.w * b.y; acc[3][2] += a.w * b.z; acc[3][3] += a.w * b.w;
    }

#pragma unroll
    for (int i = 0; i < 4; ++i) {
        int row = row0 + rg * 4 + i;
        if (row < n) {
            float dd = dinv[row];
            pk2 p;
            p.h[0] = __floats2half2_rn(acc[i][0] * dd, acc[i][1] * dd);
            p.h[1] = __floats2half2_rn(acc[i][2] * dd, acc[i][3] * dd);
            *(uint2*)&h[(size_t)row * 64 + tc * 4] = p.u;
        }
    }
}

// h2s[n,40] = (relu(agg1[n,64]) @ W2[64,40]) * dinv[row], fp16 in/out.
__global__ __launch_bounds__(256) void k_gemm2_h(const __half* __restrict__ agg,
                                                 const float* __restrict__ W2,
                                                 __half* __restrict__ h2, int n,
                                                 const float* __restrict__ dinv) {
    __shared__ float Ws[64 * 40];
    __shared__ float hsT[64 * 64];
    const int tid = threadIdx.x;
    const int row0 = blockIdx.x * 64;
    {
        const float4* Wg = (const float4*)W2;
        float4* Wl = (float4*)Ws;
        for (int i = tid; i < 640; i += 256) Wl[i] = Wg[i];
    }
    {
        int r = tid & 63, g = tid >> 6;
        int row = row0 + r;
        const __half* ar = agg + (size_t)row * 64;
#pragma unroll
        for (int t = 0; t < 4; ++t) {
            int k0 = g * 16 + t * 4;
            float4 v = make_float4(0.f, 0.f, 0.f, 0.f);
            if (row < n) {
                uint2 u = *(const uint2*)(ar + k0);
                __half2 h0 = *(__half2*)&u.x, h1 = *(__half2*)&u.y;
                float2 f0 = __half22float2(h0), f1 = __half22float2(h1);
                v = make_float4(f0.x, f0.y, f1.x, f1.y);
            }
            hsT[(k0 + 0) * 64 + r] = v.x > 0.f ? v.x : 0.f;
            hsT[(k0 + 1) * 64 + r] = v.y > 0.f ? v.y : 0.f;
            hsT[(k0 + 2) * 64 + r] = v.z > 0.f ? v.z : 0.f;
            hsT[(k0 + 3) * 64 + r] = v.w > 0.f ? v.w : 0.f;
        }
    }
    __syncthreads();

    const int tc = tid & 15;
    const int rg = tid >> 4;
    if (tc < 10) {
        float acc[4][4];
#pragma unroll
        for (int i = 0; i < 4; ++i)
#pragma unroll
            for (int j = 0; j < 4; ++j) acc[i][j] = 0.f;

#pragma unroll 4
        for (int k = 0; k < 64; ++k) {
            float4 a = *(const float4*)&hsT[k * 64 + rg * 4];
            float4 b = *(const float4*)&Ws[k * 40 + tc * 4];
            acc[0][0] += a.x * b.x; acc[0][1] += a.x * b.y; acc[0][2] += a.x * b.z; acc[0][3] += a.x * b.w;
            acc[1][0] += a.y * b.x; acc[1][1] += a.y * b.y; acc[1][2] += a.y * b.z; acc[1][3] += a.y * b.w;
            acc[2][0] += a.z * b.x; acc[2][1] += a.z * b.y; acc[2][2] += a.z * b.z; acc[2][3] += a.z * b.w;
            acc[3][0] += a.w * b.x; acc[3][1] += a.w * b.y; acc[3][2] += a.w * b.z; acc[3][3] += a.w * b.w;
        }

#pragma unroll
        for (int i = 0; i < 4; ++i) {
            int row = row0 + rg * 4 + i;
            if (row < n) {
                float dd = dinv[row];
                pk2 p;
                p.h[0] = __floats2half2_rn(acc[i][0] * dd, acc[i][1] * dd);
                p.h[1] = __floats2half2_rn(acc[i][2] * dd, acc[i][3] * dd);
                *(uint2*)&h2[(size_t)row * 40 + tc * 4] = p.u;
            }
        }
    }
}

// ---------------- gathers (fp16 rows, fp32 accumulate) ----------------

// agg1[d] = (sum_{s in in(d)} hs[s] + hs[d]) * dinv[d] + b1, fp16 out.
// Wave/node; 4 edge-groups (g) x 16 quads (q); 16 edges in flight.
__global__ __launch_bounds__(256) void k_gather1_h(const __half* __restrict__ hs,
                                                   const int* __restrict__ off,
                                                   const int* __restrict__ csrc,
                                                   const float* __restrict__ dinv,
                                                   const float4* __restrict__ b1_4,
                                                   __half* __restrict__ agg, int n) {
    int node = blockIdx.x * 4 + (threadIdx.x >> 6);
    if (node >= n) return;
    int lane = threadIdx.x & 63;
    int g = lane >> 4, q = lane & 15;
    int beg = off[node], end = off[node + 1];
    float4 a0 = make_float4(0.f, 0.f, 0.f, 0.f);
    float4 a1 = make_float4(0.f, 0.f, 0.f, 0.f);
    float4 a2 = make_float4(0.f, 0.f, 0.f, 0.f);
    float4 a3 = make_float4(0.f, 0.f, 0.f, 0.f);
    int j = beg;
    for (; j + 16 <= end; j += 16) {
        int s0 = csrc[j + g], s1 = csrc[j + 4 + g];
        int s2 = csrc[j + 8 + g], s3 = csrc[j + 12 + g];
        h4_acc(hs + (size_t)s0 * 64 + q * 4, a0);
        h4_acc(hs + (size_t)s1 * 64 + q * 4, a1);
        h4_acc(hs + (size_t)s2 * 64 + q * 4, a2);
        h4_acc(hs + (size_t)s3 * 64 + q * 4, a3);
    }
    for (; j + 8 <= end; j += 8) {
        int s0 = csrc[j + g], s1 = csrc[j + 4 + g];
        h4_acc(hs + (size_t)s0 * 64 + q * 4, a0);
        h4_acc(hs + (size_t)s1 * 64 + q * 4, a1);
    }
    for (; j < end; j += 4) {
        int jj = j + g;
        if (jj < end) {
            int s = csrc[jj];
            h4_acc(hs + (size_t)s * 64 + q * 4, a0);
        }
    }
    F4ADD(a0, a1); F4ADD(a2, a3); F4ADD(a0, a2);
    a0.x += __shfl_down(a0.x, 32); a0.y += __shfl_down(a0.y, 32);
    a0.z += __shfl_down(a0.z, 32); a0.w += __shfl_down(a0.w, 32);
    a0.x += __shfl_down(a0.x, 16); a0.y += __shfl_down(a0.y, 16);
    a0.z += __shfl_down(a0.z, 16); a0.w += __shfl_down(a0.w, 16);
    if (lane < 16) {
        float4 s = make_float4(0.f, 0.f, 0.f, 0.f);
        h4_acc(hs + (size_t)node * 64 + q * 4, s);
        float dd = dinv[node];
        float4 b = b1_4[q];
        pk2 p;
        p.h[0] = __floats2half2_rn((a0.x + s.x) * dd + b.x, (a0.y + s.y) * dd + b.y);
        p.h[1] = __floats2half2_rn((a0.z + s.z) * dd + b.z, (a0.w + s.w) * dd + b.w);
        *(uint2*)&agg[(size_t)node * 64 + q * 4] = p.u;
    }
}

// out[d] = (sum h2s[s] + h2s[d]) * dinv[d] + b2, fp32 out. 6 groups x 10 lanes.
__global__ __launch_bounds__(256) void k_gather2_h(const __half* __restrict__ h2s,
                                                   const int* __restrict__ off,
                                                   const int* __restrict__ csrc,
                                                   const float* __restrict__ dinv,
                                                   const float4* __restrict__ b2_4,
                                                   float4* __restrict__ out4, int n) {
    int node = blockIdx.x * 4 + (threadIdx.x >> 6);
    if (node >= n) return;
    int lane = threadIdx.x & 63;
    int g = lane / 10;
    int q = lane - g * 10;
    bool act = g < 6;
    int beg = off[node], end = off[node + 1];
    float4 a0 = make_float4(0.f, 0.f, 0.f, 0.f);
    float4 a1 = make_float4(0.f, 0.f, 0.f, 0.f);
    int j = beg;
    for (; j + 12 <= end; j += 12) {
        if (act) {
            int s0 = csrc[j + g], s1 = csrc[j + 6 + g];
            h4_acc(h2s + (size_t)s0 * 40 + q * 4, a0);
            h4_acc(h2s + (size_t)s1 * 40 + q * 4, a1);
        }
    }
    for (; j < end; j += 6) {
        int jj = j + g;
        if (act && jj < end) {
            int s = csrc[jj];
            h4_acc(h2s + (size_t)s * 40 + q * 4, a0);
        }
    }
    F4ADD(a0, a1);
    float4 r;
    r.x = __shfl_down(a0.x, 30); r.y = __shfl_down(a0.y, 30);
    r.z = __shfl_down(a0.z, 30); r.w = __shfl_down(a0.w, 30);
    if (lane < 30) F4ADD(a0, r);
    r.x = __shfl_down(a0.x, 20); r.y = __shfl_down(a0.y, 20);
    r.z = __shfl_down(a0.z, 20); r.w = __shfl_down(a0.w, 20);
    if (lane < 10) F4ADD(a0, r);
    r.x = __shfl_down(a0.x, 10); r.y = __shfl_down(a0.y, 10);
    r.z = __shfl_down(a0.z, 10); r.w = __shfl_down(a0.w, 10);
    if (lane < 10) F4ADD(a0, r);
    if (lane < 10) {
        float4 s = make_float4(0.f, 0.f, 0.f, 0.f);
        h4_acc(h2s + (size_t)node * 40 + q * 4, s);
        float dd = dinv[node];
        float4 b = b2_4[q];
        float4 o;
        o.x = (a0.x + s.x) * dd + b.x;
        o.y = (a0.y + s.y) * dd + b.y;
        o.z = (a0.z + s.z) * dd + b.z;
        o.w = (a0.w + s.w) * dd + b.w;
        out4[node * 10 + q] = o;
    }
}

// ---------------- fallback atomic-scatter path (fp32, proven) ----------------

__global__ void k_init_deg(float* __restrict__ deg, int n) {
    int i = blockIdx.x * blockDim.x + threadIdx.x;
    if (i < n) deg[i] = 1.0f;
}

__global__ void k_deg(const int* __restrict__ dst, int E, float* __restrict__ deg) {
    int i = blockIdx.x * blockDim.x + threadIdx.x;
    if (i < E) atomicAdd(&deg[dst[i]], 1.0f);
}

__global__ void k_rsqrt(float* __restrict__ deg, int n) {
    int i = blockIdx.x * blockDim.x + threadIdx.x;
    if (i < n) deg[i] = rsqrtf(deg[i]);
}

__global__ __launch_bounds__(256) void k_gemm1_f(const float* __restrict__ x,
                                                 const float* __restrict__ W,
                                                 float* __restrict__ h, int n) {
    __shared__ float Ws[128 * 64];
    __shared__ float xsT[128 * 64];
    const int tid = threadIdx.x;
    const int row0 = blockIdx.x * 64;
    {
        const float4* Wg = (const float4*)W;
        float4* Wl = (float4*)Ws;
#pragma unroll
        for (int t = 0; t < 8; ++t) Wl[tid + t * 256] = Wg[tid + t * 256];
    }
    {
        int r = tid & 63, g = tid >> 6;
        int row = row0 + r;
        const float4* xr = (const float4*)(x + (size_t)row * 128);
#pragma unroll
        for (int t = 0; t < 8; ++t) {
            int k0 = g * 32 + t * 4;
            float4 v = (row < n) ? xr[k0 >> 2] : make_float4(0.f, 0.f, 0.f, 0.f);
            xsT[(k0 + 0) * 64 + r] = v.x;
            xsT[(k0 + 1) * 64 + r] = v.y;
            xsT[(k0 + 2) * 64 + r] = v.z;
            xsT[(k0 + 3) * 64 + r] = v.w;
        }
    }
    __syncthreads();
    const int tc = tid & 15;
    const int rg = tid >> 4;
    float acc[4][4];
#pragma unroll
    for (int i = 0; i < 4; ++i)
#pragma unroll
        for (int j = 0; j < 4; ++j) acc[i][j] = 0.f;
#pragma unroll 4
    for (int k = 0; k < 128; ++k) {
        float4 a = *(const float4*)&xsT[k * 64 + rg * 4];
        float4 b = *(const float4*)&Ws[k * 64 + tc * 4];
        acc[0][0] += a.x * b.x; acc[0][1] += a.x * b.y; acc[0][2] += a.x * b.z; acc[0][3] += a.x * b.w;
        acc[1][0] += a.y * b.x; acc[1][1] += a.y * b.y; acc[1][2] += a.y * b.z; acc[1][3] += a.y * b.w;
        acc[2][0] += a.z * b.x; acc[2][1] += a.z * b.y; acc[2][2] += a.z * b.z; acc[2][3] += a.z * b.w;
        acc[3][0] += a.w * b.x; acc[3][1] += a.w * b.y; acc[3][2] += a.w * b.z; acc[3][3] += a.w * b.w;
    }
#pragma unroll
    for (int i = 0; i < 4; ++i) {
        int row = row0 + rg * 4 + i;
        if (row < n)
            *(float4*)&h[(size_t)row * 64 + tc * 4] =
                make_float4(acc[i][0], acc[i][1], acc[i][2], acc[i][3]);
    }
}

__global__ __launch_bounds__(256) void k_gemm2_f(const float* __restrict__ agg,
                                                 const float* __restrict__ W2,
                                                 float* __restrict__ h2, int n) {
    __shared__ float Ws[64 * 40];
    __shared__ float hsT[64 * 64];
    const int tid = threadIdx.x;
    const int row0 = blockIdx.x * 64;
    {
        const float4* Wg = (const float4*)W2;
        float4* Wl = (float4*)Ws;
        for (int i = tid; i < 640; i += 256) Wl[i] = Wg[i];
    }
    {
        int r = tid & 63, g = tid >> 6;
        int row = row0 + r;
        const float4* ar = (const float4*)(agg + (size_t)row * 64);
#pragma unroll
        for (int t = 0; t < 4; ++t) {
            int k0 = g * 16 + t * 4;
            float4 v = (row < n) ? ar[k0 >> 2] : make_float4(0.f, 0.f, 0.f, 0.f);
            hsT[(k0 + 0) * 64 + r] = v.x > 0.f ? v.x : 0.f;
            hsT[(k0 + 1) * 64 + r] = v.y > 0.f ? v.y : 0.f;
            hsT[(k0 + 2) * 64 + r] = v.z > 0.f ? v.z : 0.f;
            hsT[(k0 + 3) * 64 + r] = v.w > 0.f ? v.w : 0.f;
        }
    }
    __syncthreads();
    const int tc = tid & 15;
    const int rg = tid >> 4;
    if (tc < 10) {
        float acc[4][4];
#pragma unroll
        for (int i = 0; i < 4; ++i)
#pragma unroll
            for (int j = 0; j < 4; ++j) acc[i][j] = 0.f;
#pragma unroll 4
        for (int k = 0; k < 64; ++k) {
            float4 a = *(const float4*)&hsT[k * 64 + rg * 4];
            float4 b = *(const float4*)&Ws[k * 40 + tc * 4];
            acc[0][0] += a.x * b.x; acc[0][1] += a.x * b.y; acc[0][2] += a.x * b.z; acc[0][3] += a.x * b.w;
            acc[1][0] += a.y * b.x; acc[1][1] += a.y * b.y; acc[1][2] += a.y * b.z; acc[1][3] += a.y * b.w;
            acc[2][0] += a.z * b.x; acc[2][1] += a.z * b.y; acc[2][2] += a.z * b.z; acc[2][3] += a.z * b.w;
            acc[3][0] += a.w * b.x; acc[3][1] += a.w * b.y; acc[3][2] += a.w * b.z; acc[3][3] += a.w * b.w;
        }
#pragma unroll
        for (int i = 0; i < 4; ++i) {
            int row = row0 + rg * 4 + i;
            if (row < n)
                *(float4*)&h2[(size_t)row * 40 + tc * 4] =
                    make_float4(acc[i][0], acc[i][1], acc[i][2], acc[i][3]);
        }
    }
}

__global__ void k_init_agg1(const float* __restrict__ h, const float* __restrict__ dinv,
                            const float* __restrict__ b1, float* __restrict__ agg, int n) {
    int idx = blockIdx.x * blockDim.x + threadIdx.x;
    if (idx < n * 64) {
        int i = idx >> 6, f = idx & 63;
        float d = dinv[i];
        agg[idx] = h[idx] * d * d + b1[f];
    }
}

__global__ __launch_bounds__(256) void k_scatter1(const float* __restrict__ h,
                                                  const int* __restrict__ src,
                                                  const int* __restrict__ dst,
                                                  const float* __restrict__ dinv,
                                                  float* __restrict__ agg, int E) {
    int e = blockIdx.x * 4 + (threadIdx.x >> 6);
    if (e >= E) return;
    int f = threadIdx.x & 63;
    int s = src[e], d = dst[e];
    float w = dinv[s] * dinv[d];
    atomicAdd(&agg[d * 64 + f], h[s * 64 + f] * w);
}

__global__ void k_init_out(const float* __restrict__ h2, const float* __restrict__ dinv,
                           const float* __restrict__ b2, float* __restrict__ out, int n) {
    int idx = blockIdx.x * blockDim.x + threadIdx.x;
    if (idx < n * 40) {
        int i = idx / 40;
        int f = idx - i * 40;
        float d = dinv[i];
        out[idx] = h2[idx] * d * d + b2[f];
    }
}

__global__ __launch_bounds__(256) void k_scatter2(const float* __restrict__ h2,
                                                  const int* __restrict__ src,
                                                  const int* __restrict__ dst,
                                                  const float* __restrict__ dinv,
                                                  float* __restrict__ out, int E) {
    int idx = blockIdx.x * blockDim.x + threadIdx.x;
    int total = E * 40;
    if (idx >= total) return;
    int e = idx / 40;
    int f = idx - e * 40;
    int s = src[e], d = dst[e];
    float w = dinv[s] * dinv[d];
    atomicAdd(&out[d * 40 + f], h2[s * 40 + f] * w);
}

extern "C" void kernel_launch(void* const* d_in, const int* in_sizes, int n_in,
                              void* d_out, int out_size, void* d_ws, size_t ws_size,
                              hipStream_t stream) {
    const float* x  = (const float*)d_in[0];
    const int*   ei = (const int*)d_in[1];
    const float* W1 = (const float*)d_in[2];
    const float* b1 = (const float*)d_in[3];
    const float* W2 = (const float*)d_in[4];
    const float* b2 = (const float*)d_in[5];
    float* out = (float*)d_out;

    const int n = in_sizes[0] / 128;   // 100000
    const int E = in_sizes[1] / 2;     // 1600000
    const int* src = ei;
    const int* dst = ei + E;

    char* ws = (char*)d_ws;
    const size_t MB = 1 << 20;
    // fast-path layout (fp16 intermediates): 35MB + E*4 needed
    float*  dinv   = (float*)(ws);                       // n floats
    int*    off    = (int*)  (ws + 512 * 1024);          // n+1 ints
    int*    bcnt   = (int*)  (ws + 1 * MB);              // NBCAP ints
    int*    bbase  = (int*)  (ws + 1 * MB + 8 * 1024);   // NBCAP+1 ints
    int*    bcur   = (int*)  (ws + 1 * MB + 16 * 1024);  // NBCAP ints
    __half* hs_h   = (__half*)(ws + 2 * MB);             // n*64 halves (12.8MB)
    __half* agg1_h = (__half*)(ws + 15 * MB);            // n*64 halves (12.8MB)
    __half* h2s_h  = hs_h;                               // reuse (hs dead after gemm2)
    int*    pairs  = (int*)  (ws + 28 * MB);             // E ints
    int*    csrc   = (int*)  (ws + 35 * MB);             // E ints
    size_t needed_fast = 35 * MB + (size_t)E * 4;

    const int nb = (n + NPB - 1) / NPB;

    if (ws_size >= needed_fast && nb <= NBCAP && n <= (1 << 17)) {
        // ---- CSC build via counting sort ----
        k_zero<<<(nb + 255) / 256, 256, 0, stream>>>(bcnt, nb);
        k_hist<<<512, 256, 0, stream>>>(dst, E, bcnt, nb);
        k_scan_nb<<<1, 1024, 0, stream>>>(bcnt, bbase, bcur, nb);
        k_binpass<<<(E + 4095) / 4096, 256, 0, stream>>>(src, dst, bcur, pairs, nb, E);
        k_bucket_build<<<nb, 256, 0, stream>>>(pairs, bbase, off, csrc, dinv, n, nb);

        // ---- layer 1 ----
        k_gemm1_h<<<(n + 63) / 64, 256, 0, stream>>>(x, W1, hs_h, n, dinv);
        k_gather1_h<<<(n + 3) / 4, 256, 0, stream>>>(hs_h, off, csrc, dinv,
                                                     (const float4*)b1, agg1_h, n);
        // ---- layer 2 ----
        k_gemm2_h<<<(n + 63) / 64, 256, 0, stream>>>(agg1_h, W2, h2s_h, n, dinv);
        k_gather2_h<<<(n + 3) / 4, 256, 0, stream>>>(h2s_h, off, csrc, dinv,
                                                     (const float4*)b2, (float4*)out, n);
    } else {
        // ---- fallback: fp32 atomic scatter path (round-1 proven) ----
        float* hlin = (float*)(ws + 2 * MB);              // n*64 floats
        float* agg1 = (float*)(ws + 28 * MB);             // n*64 floats
        k_init_deg<<<(n + 255) / 256, 256, 0, stream>>>(dinv, n);
        k_deg<<<(E + 255) / 256, 256, 0, stream>>>(dst, E, dinv);
        k_rsqrt<<<(n + 255) / 256, 256, 0, stream>>>(dinv, n);
        k_gemm1_f<<<(n + 63) / 64, 256, 0, stream>>>(x, W1, hlin, n);
        k_init_agg1<<<(n * 64 + 255) / 256, 256, 0, stream>>>(hlin, dinv, b1, agg1, n);
        k_scatter1<<<(E + 3) / 4, 256, 0, stream>>>(hlin, src, dst, dinv, agg1, E);
        k_gemm2_f<<<(n + 63) / 64, 256, 0, stream>>>(agg1, W2, hlin, n);
        k_init_out<<<(n * 40 + 255) / 256, 256, 0, stream>>>(hlin, dinv, b2, out, n);
        int total2 = E * 40;
        k_scatter2<<<(total2 + 255) / 256, 256, 0, stream>>>(hlin, src, dst, dinv, out, E);
    }
}